// Round 5
// baseline (151.857 us; speedup 1.0000x reference)
//
#include <hip/hip_runtime.h>
#include <math.h>

#define BATCHN 4096
#define DMODEL 1024
#define NT 64
#define RANK 8
#define K2 512   // NT*RANK

typedef __attribute__((ext_vector_type(8))) short bf16x8;
typedef __attribute__((ext_vector_type(4))) float f32x4;

__device__ __forceinline__ void async16(void* lds, const void* g) {
    __builtin_amdgcn_global_load_lds(
        (const __attribute__((address_space(1))) void*)g,
        (__attribute__((address_space(3))) void*)lds, 16, 0, 0);
}

__device__ __forceinline__ short f2bf(float f) {
    unsigned u = __builtin_bit_cast(unsigned, f);
    u += 0x7fffu + ((u >> 16) & 1u);   // round-to-nearest-even
    return (short)(u >> 16);
}

__device__ __forceinline__ bf16x8 cvt8(const float4 a, const float4 b) {
    bf16x8 o;
    o[0]=f2bf(a.x); o[1]=f2bf(a.y); o[2]=f2bf(a.z); o[3]=f2bf(a.w);
    o[4]=f2bf(b.x); o[5]=f2bf(b.y); o[6]=f2bf(b.z); o[7]=f2bf(b.w);
    return o;
}

// ---- K1: gate + raw-vx GEMM, fp32 inputs converted in-register (no convert pass).
// C = bf16(x) @ bf16([enc;V])^T. grid (10,64), BM=64 BN=64 BK=64.
// bn==0: gate = relu(C - bias); bn in 1..8: vx = bf16(C) raw.
// bn==9: U_n -> Ub bf16 (native [n][d][r]) + su_part[n] sumsq (n = bm).
// bm==0, bn>=1 blocks also accumulate sv_part[n] = sum(V_n^2) during B staging.
// NOTE: pure function of inputs (idempotent) — launched twice this round as a
// timing discriminator: dur_delta vs round 4 == (K1+K2) warm execution time.
__global__ __launch_bounds__(256) void gatevx_kernel(
    const float* __restrict__ x, const float* __restrict__ enc,
    const float* __restrict__ V, const float* __restrict__ U,
    const float* __restrict__ bias,
    float* __restrict__ gate_out, unsigned short* __restrict__ vx_out,
    unsigned short* __restrict__ Ub,
    float* __restrict__ su_part, float* __restrict__ sv_part)
{
    __shared__ unsigned short As[2][4096];   // 8 KB x2 (epilogue reuses as C)
    __shared__ unsigned short Bs[2][4096];
    __shared__ float red[4];
    const int t = threadIdx.x;
    const int bn = blockIdx.x, bm = blockIdx.y;
    const int wave = t >> 6, lane = t & 63;

    if (bn == 9) {           // U convert + sumsq, one n per block (n = bm)
        const int n = bm;
        const size_t base = (size_t)n * 8192;
        float s = 0.f;
        #pragma unroll
        for (int it = 0; it < 4; ++it) {
            const size_t e = base + it * 2048 + t * 8;
            float4 v0 = *(const float4*)(U + e);
            float4 v1 = *(const float4*)(U + e + 4);
            *(bf16x8*)(Ub + e) = cvt8(v0, v1);
            s += v0.x*v0.x + v0.y*v0.y + v0.z*v0.z + v0.w*v0.w
               + v1.x*v1.x + v1.y*v1.y + v1.z*v1.z + v1.w*v1.w;
        }
        #pragma unroll
        for (int off = 32; off; off >>= 1) s += __shfl_down(s, off);
        if ((t & 63) == 0) red[t >> 6] = s;
        __syncthreads();
        if (t == 0) su_part[n] = red[0] + red[1] + red[2] + red[3];
        return;
    }

    constexpr int BK = 64, KDIM = DMODEL, NIT = KDIM / BK;  // 16 iters
    const int wm = wave & 1, wn = wave >> 1;
    const int lrow = lane >> 3, lchunk = lane & 7;
    const int l15 = lane & 15, lq = lane >> 4;

    f32x4 acc[2][2] = {};
    const size_t Arow0 = (size_t)bm * 64;
    const float* Bbase = (bn == 0) ? enc : V + (size_t)(bn - 1) * 64 * DMODEL;
    const bool doSV = (bn >= 1) && (bm == 0);
    float sv[2] = {0.f, 0.f};

    // T14 split: LOAD issues global f32 loads; WRITE converts + ds_writes.
    auto LOADAB = [&](int k0, float4* a, float4* b) {
        #pragma unroll
        for (int c = 0; c < 2; ++c) {
            const int row = (wave * 2 + c) * 8 + lrow;
            const int chunk = lchunk ^ lrow;
            const float* ax = x + (Arow0 + row) * DMODEL + k0 + chunk * 8;
            a[c*2]   = *(const float4*)ax;
            a[c*2+1] = *(const float4*)(ax + 4);
            const float* bx = Bbase + (size_t)row * DMODEL + k0 + chunk * 8;
            b[c*2]   = *(const float4*)bx;
            b[c*2+1] = *(const float4*)(bx + 4);
        }
    };
    auto WRITEAB = [&](int buf, const float4* a, const float4* b) {
        #pragma unroll
        for (int c = 0; c < 2; ++c) {
            *(bf16x8*)&As[buf][(wave * 2 + c) * 512 + lane * 8] = cvt8(a[c*2], a[c*2+1]);
            *(bf16x8*)&Bs[buf][(wave * 2 + c) * 512 + lane * 8] = cvt8(b[c*2], b[c*2+1]);
            if (doSV) {
                const float4 b0 = b[c*2], b1 = b[c*2+1];
                sv[c] += b0.x*b0.x + b0.y*b0.y + b0.z*b0.z + b0.w*b0.w
                       + b1.x*b1.x + b1.y*b1.y + b1.z*b1.z + b1.w*b1.w;
            }
        }
    };
    auto COMPUTE = [&](int buf) {
        #pragma unroll
        for (int s = 0; s < 2; ++s) {
            bf16x8 af[2], bfr[2];
            const int kc = s * 4 + lq;
            #pragma unroll
            for (int i = 0; i < 2; ++i) {
                const int m = wm * 32 + i * 16 + l15;
                af[i] = *(const bf16x8*)&As[buf][m * BK + ((kc ^ (m & 7)) * 8)];
            }
            #pragma unroll
            for (int j = 0; j < 2; ++j) {
                const int n = wn * 32 + j * 16 + l15;
                bfr[j] = *(const bf16x8*)&Bs[buf][n * BK + ((kc ^ (n & 7)) * 8)];
            }
            #pragma unroll
            for (int i = 0; i < 2; ++i)
                #pragma unroll
                for (int j = 0; j < 2; ++j)
                    acc[i][j] = __builtin_amdgcn_mfma_f32_16x16x32_bf16(
                        af[i], bfr[j], acc[i][j], 0, 0, 0);
        }
    };

    {   // prologue: stage tile 0
        float4 a[4], b[4];
        LOADAB(0, a, b);
        WRITEAB(0, a, b);
    }
    __syncthreads();
    int cur = 0;
    for (int kt = 0; kt < NIT - 1; ++kt) {
        float4 a[4], b[4];
        LOADAB((kt + 1) * BK, a, b);   // f32 loads in flight across MFMA
        COMPUTE(cur);
        WRITEAB(cur ^ 1, a, b);        // cvt + ds_write after compute
        __syncthreads();
        cur ^= 1;
    }
    COMPUTE(cur);

    if (doSV) {                        // finalize V sumsq: one n per (wave,c)
        #pragma unroll
        for (int c = 0; c < 2; ++c) {
            float s = sv[c];
            #pragma unroll
            for (int off = 32; off; off >>= 1) s += __shfl_down(s, off);
            if (lane == 0) sv_part[(bn - 1) * 8 + wave * 2 + c] = s;
        }
    }
    __syncthreads();                   // done reading LDS; reuse As as C staging

    if (bn == 0) {
        float* Cs = (float*)&As[0][0];           // 64x64 f32 = 16 KB
        #pragma unroll
        for (int i = 0; i < 2; ++i) {
            const int rowb = wm * 32 + i * 16 + lq * 4;
            #pragma unroll
            for (int j = 0; j < 2; ++j) {
                const int col = wn * 32 + j * 16 + l15;
                const float bz = bias[col];
                #pragma unroll
                for (int r = 0; r < 4; ++r) {
                    const float p = acc[i][j][r] - bz;
                    Cs[(rowb + r) * 64 + col] = p > 0.f ? p : 0.f;
                }
            }
        }
        __syncthreads();
        #pragma unroll
        for (int p = 0; p < 4; ++p) {            // 256B-contiguous rows
            const int row = p * 16 + (t >> 4);
            const int col = (t & 15) * 4;
            *(f32x4*)&gate_out[(size_t)(bm * 64 + row) * NT + col] =
                *(const f32x4*)&Cs[row * 64 + col];
        }
    } else {
        unsigned short* Cs16 = &As[0][0];        // 64x64 bf16 = 8 KB
        #pragma unroll
        for (int i = 0; i < 2; ++i) {
            const int rowb = wm * 32 + i * 16 + lq * 4;
            #pragma unroll
            for (int j = 0; j < 2; ++j) {
                const int col = wn * 32 + j * 16 + l15;
                #pragma unroll
                for (int r = 0; r < 4; ++r)
                    Cs16[(rowb + r) * 64 + col] = (unsigned short)f2bf(acc[i][j][r]);
            }
        }
        __syncthreads();
        #pragma unroll
        for (int p = 0; p < 2; ++p) {            // 128B-contiguous row chunks
            const int row = p * 32 + (t >> 3);
            const int chunk = t & 7;
            *(bf16x8*)&vx_out[(size_t)(bm * 64 + row) * K2 + (bn - 1) * 64 + chunk * 8] =
                *(const bf16x8*)&Cs16[row * 64 + chunk * 8];
        }
    }
}

// ---- K2: out = (gate ⊙ vx) @ U^T (U native [n][d][r] bf16). grid (8,64),
// BM=64 BN=128 BK=64, KDIM=512. Gating folded into A-staging; T14 split.
// Epilogue stages C (64x128 f32, 32KB in Bs) for 512B-coalesced out stores.
// Idempotent (see K1 note).
__global__ __launch_bounds__(256) void out_kernel(
    const unsigned short* __restrict__ vx, const float* __restrict__ gate,
    const unsigned short* __restrict__ Ub, float* __restrict__ out,
    const float* __restrict__ su_part, const float* __restrict__ sv_part,
    float* __restrict__ fro)
{
    constexpr int BK = 64, KDIM = K2, NIT = KDIM / BK;   // 8 iters
    __shared__ unsigned short As[2][4096];               // 16 KB
    __shared__ unsigned short Bs[2][8192];               // 32 KB (also C staging)
    const int t = threadIdx.x;
    const int wave = t >> 6, lane = t & 63;
    const int bm = blockIdx.y, bn = blockIdx.x;
    const int wm = wave & 1, wn = wave >> 1;
    const int lrow = lane >> 3, lchunk = lane & 7;
    const int l15 = lane & 15, lq = lane >> 4;

    f32x4 acc[2][4] = {};

    auto LOADA = [&](int k0, bf16x8* v, float* g) {
        #pragma unroll
        for (int c = 0; c < 2; ++c) {
            const int row = (wave * 2 + c) * 8 + lrow;
            const int grow = bm * 64 + row;
            const int chunk = lchunk ^ lrow;
            v[c] = *(const bf16x8*)(vx + (size_t)grow * K2 + k0 + chunk * 8);
            g[c] = gate[(size_t)grow * NT + (k0 >> 3) + chunk];
        }
    };
    auto WRITEA = [&](int buf, const bf16x8* v, const float* g) {
        #pragma unroll
        for (int c = 0; c < 2; ++c) {
            bf16x8 o;
            #pragma unroll
            for (int e = 0; e < 8; ++e) {
                const float f = __builtin_bit_cast(float,
                    ((unsigned)(unsigned short)v[c][e]) << 16);
                o[e] = (short)(__builtin_bit_cast(unsigned, f * g[c]) >> 16);  // trunc
            }
            *(bf16x8*)&As[buf][(wave * 2 + c) * 512 + lane * 8] = o;
        }
    };
    auto STAGEB = [&](int buf, int k0) {
        #pragma unroll
        for (int c = 0; c < 4; ++c) {
            const int n_local = wave * 2 + (c >> 1);
            const int dblk = c & 1;
            const int n_glob = (k0 >> 3) + n_local;
            async16(&Bs[buf][(n_local * 2 + dblk) * 512],
                    Ub + (size_t)n_glob * (DMODEL * RANK)
                       + (size_t)(bn * 128 + dblk * 64 + lane) * RANK);
        }
    };
    auto COMPUTE = [&](int buf) {
        #pragma unroll
        for (int s = 0; s < 2; ++s) {
            bf16x8 af[2], bfr[4];
            const int kc = s * 4 + lq;   // = n_local
            #pragma unroll
            for (int i = 0; i < 2; ++i) {
                const int m = wm * 32 + i * 16 + l15;
                af[i] = *(const bf16x8*)&As[buf][m * BK + ((kc ^ (m & 7)) * 8)];
            }
            #pragma unroll
            for (int j = 0; j < 4; ++j) {
                const int cl = wn * 64 + j * 16 + l15;
                bfr[j] = *(const bf16x8*)&Bs[buf][((kc * 2 + (cl >> 6)) * 64 + (cl & 63)) * 8];
            }
            #pragma unroll
            for (int i = 0; i < 2; ++i)
                #pragma unroll
                for (int j = 0; j < 4; ++j)
                    acc[i][j] = __builtin_amdgcn_mfma_f32_16x16x32_bf16(
                        af[i], bfr[j], acc[i][j], 0, 0, 0);
        }
    };

    {   // prologue
        bf16x8 v[2]; float g[2];
        LOADA(0, v, g);
        STAGEB(0, 0);
        WRITEA(0, v, g);
    }
    __syncthreads();
    int cur = 0;
    for (int kt = 0; kt < NIT - 1; ++kt) {
        bf16x8 v[2]; float g[2];
        LOADA((kt + 1) * BK, v, g);
        STAGEB(cur ^ 1, (kt + 1) * BK);
        COMPUTE(cur);
        WRITEA(cur ^ 1, v, g);
        __syncthreads();
        cur ^= 1;
    }
    COMPUTE(cur);
    __syncthreads();                 // done reading LDS; reuse Bs as C staging

    float* Cs = (float*)&Bs[0][0];   // 64x128 f32 = 32 KB
    #pragma unroll
    for (int i = 0; i < 2; ++i) {
        const int rowb = wm * 32 + i * 16 + lq * 4;
        #pragma unroll
        for (int j = 0; j < 4; ++j) {
            const int col = wn * 64 + j * 16 + l15;
            #pragma unroll
            for (int r = 0; r < 4; ++r)
                Cs[(rowb + r) * 128 + col] = acc[i][j][r];
        }
    }
    __syncthreads();
    #pragma unroll
    for (int p = 0; p < 8; ++p) {    // 512B-contiguous rows
        const int row = p * 8 + (t >> 5);
        const int col = (t & 31) * 4;
        *(f32x4*)&out[(size_t)(bm * 64 + row) * DMODEL + bn * 128 + col] =
            *(const f32x4*)&Cs[row * 128 + col];
    }

    // finalize Frobenius norms (K1 wrote su/sv; kernel boundary = coherence)
    if (bn == 0 && bm == 0 && t < NT) {
        fro[t] = sqrtf(su_part[t]) * sqrtf(sv_part[t]) / sqrtf((float)(DMODEL * RANK));
    }
}

extern "C" void kernel_launch(void* const* d_in, const int* in_sizes, int n_in,
                              void* d_out, int out_size, void* d_ws, size_t ws_size,
                              hipStream_t stream) {
    const float* x    = (const float*)d_in[0];
    const float* V    = (const float*)d_in[1];
    const float* U    = (const float*)d_in[2];
    const float* enc  = (const float*)d_in[3];
    const float* bias = (const float*)d_in[4];

    float* out  = (float*)d_out;                       // [4096,1024]
    float* gate = out + (size_t)BATCHN * DMODEL;       // [4096,64] fp32
    float* fro  = gate + (size_t)BATCHN * NT;          // [64]

    char* ws = (char*)d_ws;
    unsigned short* Ub = (unsigned short*)ws;                    // 1,048,576 B
    unsigned short* vx = (unsigned short*)(ws + 1048576);        // 4,194,304 B
    float* su_part     = (float*)(ws + 5242880);                 // 256 B
    float* sv_part     = (float*)(ws + 5244928);                 // 256 B

    // DISCRIMINATOR ROUND: each kernel launched twice (idempotent, bit-identical
    // output). dur_us(round5) - dur_us(round4) == warm (K1 + K2) time, giving
    // ground truth on how much of the ~110 us window our kernels actually occupy.
    gatevx_kernel<<<dim3(10, 64), 256, 0, stream>>>(
        x, enc, V, U, bias, gate, vx, Ub, su_part, sv_part);
    gatevx_kernel<<<dim3(10, 64), 256, 0, stream>>>(
        x, enc, V, U, bias, gate, vx, Ub, su_part, sv_part);
    out_kernel<<<dim3(8, 64), 256, 0, stream>>>(
        vx, gate, Ub, out, su_part, sv_part, fro);
    out_kernel<<<dim3(8, 64), 256, 0, stream>>>(
        vx, gate, Ub, out, su_part, sv_part, fro);
}

// Round 6
// 103.190 us; speedup vs baseline: 1.4716x; 1.4716x over previous
//
#include <hip/hip_runtime.h>
#include <math.h>

#define BATCHN 4096
#define DMODEL 1024
#define NT 64
#define RANK 8
#define K2 512   // NT*RANK

typedef __attribute__((ext_vector_type(8))) short bf16x8;
typedef __attribute__((ext_vector_type(4))) float f32x4;

__device__ __forceinline__ void async16(void* lds, const void* g) {
    __builtin_amdgcn_global_load_lds(
        (const __attribute__((address_space(1))) void*)g,
        (__attribute__((address_space(3))) void*)lds, 16, 0, 0);
}

__device__ __forceinline__ short f2bf(float f) {
    unsigned u = __builtin_bit_cast(unsigned, f);
    u += 0x7fffu + ((u >> 16) & 1u);   // round-to-nearest-even
    return (short)(u >> 16);
}

__device__ __forceinline__ bf16x8 cvt8(const float4 a, const float4 b) {
    bf16x8 o;
    o[0]=f2bf(a.x); o[1]=f2bf(a.y); o[2]=f2bf(a.z); o[3]=f2bf(a.w);
    o[4]=f2bf(b.x); o[5]=f2bf(b.y); o[6]=f2bf(b.z); o[7]=f2bf(b.w);
    return o;
}

// ---- K1: gate + raw-vx GEMM, fp32 inputs converted in-register.
// 1D grid 640, XCD-swizzled: wgid<576 -> GEMM (bm=wgid/9, bn=wgid%9);
// wgid>=576 -> U_n convert + su_part (n = wgid-576).
// 2-deep register prefetch: loads for tile t+2 issued at iter t (latency ~1.5 iters).
__global__ __launch_bounds__(256) void gatevx_kernel(
    const float* __restrict__ x, const float* __restrict__ enc,
    const float* __restrict__ V, const float* __restrict__ U,
    const float* __restrict__ bias,
    float* __restrict__ gate_out, unsigned short* __restrict__ vx_out,
    unsigned short* __restrict__ Ub,
    float* __restrict__ su_part, float* __restrict__ sv_part)
{
    __shared__ unsigned short As[2][4096];   // 8 KB x2 (epilogue reuses as C)
    __shared__ unsigned short Bs[2][4096];
    __shared__ float red[4];
    const int t = threadIdx.x;
    const int bid = blockIdx.x;
    // XCD-aware swizzle: 640 blocks, 8 XCDs, 80-block contiguous chunks.
    const int wgid = (bid & 7) * 80 + (bid >> 3);
    const int wave = t >> 6, lane = t & 63;

    if (wgid >= 576) {       // U convert + sumsq, one n per block
        const int n = wgid - 576;
        const size_t base = (size_t)n * 8192;
        float s = 0.f;
        #pragma unroll
        for (int it = 0; it < 4; ++it) {
            const size_t e = base + it * 2048 + t * 8;
            float4 v0 = *(const float4*)(U + e);
            float4 v1 = *(const float4*)(U + e + 4);
            *(bf16x8*)(Ub + e) = cvt8(v0, v1);
            s += v0.x*v0.x + v0.y*v0.y + v0.z*v0.z + v0.w*v0.w
               + v1.x*v1.x + v1.y*v1.y + v1.z*v1.z + v1.w*v1.w;
        }
        #pragma unroll
        for (int off = 32; off; off >>= 1) s += __shfl_down(s, off);
        if ((t & 63) == 0) red[t >> 6] = s;
        __syncthreads();
        if (t == 0) su_part[n] = red[0] + red[1] + red[2] + red[3];
        return;
    }

    constexpr int BK = 64, KDIM = DMODEL, NIT = KDIM / BK;  // 16 iters (even)
    const int bm = wgid / 9, bn = wgid % 9;
    const int wm = wave & 1, wn = wave >> 1;
    const int lrow = lane >> 3, lchunk = lane & 7;
    const int l15 = lane & 15, lq = lane >> 4;

    f32x4 acc[2][2] = {};
    const size_t Arow0 = (size_t)bm * 64;
    const float* Bbase = (bn == 0) ? enc : V + (size_t)(bn - 1) * 64 * DMODEL;
    const bool doSV = (bn >= 1) && (bm == 0);
    float sv[2] = {0.f, 0.f};

    auto LOADAB = [&](int k0, float4* a, float4* b) {
        #pragma unroll
        for (int c = 0; c < 2; ++c) {
            const int row = (wave * 2 + c) * 8 + lrow;
            const int chunk = lchunk ^ lrow;
            const float* ax = x + (Arow0 + row) * DMODEL + k0 + chunk * 8;
            a[c*2]   = *(const float4*)ax;
            a[c*2+1] = *(const float4*)(ax + 4);
            const float* bx = Bbase + (size_t)row * DMODEL + k0 + chunk * 8;
            b[c*2]   = *(const float4*)bx;
            b[c*2+1] = *(const float4*)(bx + 4);
        }
    };
    auto WRITEAB = [&](int buf, const float4* a, const float4* b) {
        #pragma unroll
        for (int c = 0; c < 2; ++c) {
            *(bf16x8*)&As[buf][(wave * 2 + c) * 512 + lane * 8] = cvt8(a[c*2], a[c*2+1]);
            *(bf16x8*)&Bs[buf][(wave * 2 + c) * 512 + lane * 8] = cvt8(b[c*2], b[c*2+1]);
            if (doSV) {
                const float4 b0 = b[c*2], b1 = b[c*2+1];
                sv[c] += b0.x*b0.x + b0.y*b0.y + b0.z*b0.z + b0.w*b0.w
                       + b1.x*b1.x + b1.y*b1.y + b1.z*b1.z + b1.w*b1.w;
            }
        }
    };
    auto COMPUTE = [&](int buf) {
        #pragma unroll
        for (int s = 0; s < 2; ++s) {
            bf16x8 af[2], bfr[2];
            const int kc = s * 4 + lq;
            #pragma unroll
            for (int i = 0; i < 2; ++i) {
                const int m = wm * 32 + i * 16 + l15;
                af[i] = *(const bf16x8*)&As[buf][m * BK + ((kc ^ (m & 7)) * 8)];
            }
            #pragma unroll
            for (int j = 0; j < 2; ++j) {
                const int n = wn * 32 + j * 16 + l15;
                bfr[j] = *(const bf16x8*)&Bs[buf][n * BK + ((kc ^ (n & 7)) * 8)];
            }
            #pragma unroll
            for (int i = 0; i < 2; ++i)
                #pragma unroll
                for (int j = 0; j < 2; ++j)
                    acc[i][j] = __builtin_amdgcn_mfma_f32_16x16x32_bf16(
                        af[i], bfr[j], acc[i][j], 0, 0, 0);
        }
    };

    // 2-deep pipeline, even-pair unrolled loop (named reg sets, no runtime index).
    float4 a0[4], b0[4], a1[4], b1[4];
    LOADAB(0, a0, b0);
    WRITEAB(0, a0, b0);            // tile 0 -> LDS[0]
    LOADAB(BK, a1, b1);            // tile 1 in flight
    __syncthreads();
    for (int kt = 0; kt < NIT; kt += 2) {
        // iter kt: LDS[0] = tile kt; a1/b1 = tile kt+1 data
        if (kt + 2 < NIT) LOADAB((kt + 2) * BK, a0, b0);
        COMPUTE(0);
        WRITEAB(1, a1, b1);        // tile kt+1 -> LDS[1] (loads issued 1.5 iters ago)
        __syncthreads();
        // iter kt+1: LDS[1] = tile kt+1; a0/b0 = tile kt+2 data
        if (kt + 3 < NIT) LOADAB((kt + 3) * BK, a1, b1);
        COMPUTE(1);
        if (kt + 2 < NIT) WRITEAB(0, a0, b0);
        __syncthreads();
    }

    if (doSV) {                        // finalize V sumsq: one n per (wave,c)
        #pragma unroll
        for (int c = 0; c < 2; ++c) {
            float s = sv[c];
            #pragma unroll
            for (int off = 32; off; off >>= 1) s += __shfl_down(s, off);
            if (lane == 0) sv_part[(bn - 1) * 8 + wave * 2 + c] = s;
        }
    }

    if (bn == 0) {
        float* Cs = (float*)&As[0][0];           // 64x64 f32 = 16 KB
        #pragma unroll
        for (int i = 0; i < 2; ++i) {
            const int rowb = wm * 32 + i * 16 + lq * 4;
            #pragma unroll
            for (int j = 0; j < 2; ++j) {
                const int col = wn * 32 + j * 16 + l15;
                const float bz = bias[col];
                #pragma unroll
                for (int r = 0; r < 4; ++r) {
                    const float p = acc[i][j][r] - bz;
                    Cs[(rowb + r) * 64 + col] = p > 0.f ? p : 0.f;
                }
            }
        }
        __syncthreads();
        #pragma unroll
        for (int p = 0; p < 4; ++p) {            // 256B-contiguous rows
            const int row = p * 16 + (t >> 4);
            const int col = (t & 15) * 4;
            *(f32x4*)&gate_out[(size_t)(bm * 64 + row) * NT + col] =
                *(const f32x4*)&Cs[row * 64 + col];
        }
    } else {
        unsigned short* Cs16 = &As[0][0];        // 64x64 bf16 = 8 KB
        #pragma unroll
        for (int i = 0; i < 2; ++i) {
            const int rowb = wm * 32 + i * 16 + lq * 4;
            #pragma unroll
            for (int j = 0; j < 2; ++j) {
                const int col = wn * 32 + j * 16 + l15;
                #pragma unroll
                for (int r = 0; r < 4; ++r)
                    Cs16[(rowb + r) * 64 + col] = (unsigned short)f2bf(acc[i][j][r]);
            }
        }
        __syncthreads();
        #pragma unroll
        for (int p = 0; p < 2; ++p) {            // 128B-contiguous row chunks
            const int row = p * 32 + (t >> 3);
            const int chunk = t & 7;
            *(bf16x8*)&vx_out[(size_t)(bm * 64 + row) * K2 + (bn - 1) * 64 + chunk * 8] =
                *(const bf16x8*)&Cs16[row * 64 + chunk * 8];
        }
    }
}

// ---- K2: out = (gate ⊙ vx) @ U^T (U native [n][d][r] bf16). 1D grid 512,
// XCD-swizzled. BM=64 BN=128 BK=64, KDIM=512. Gating folded into A-staging;
// 2-deep A-register prefetch; B via async16 1-ahead (barrier-synced).
__global__ __launch_bounds__(256) void out_kernel(
    const unsigned short* __restrict__ vx, const float* __restrict__ gate,
    const unsigned short* __restrict__ Ub, float* __restrict__ out,
    const float* __restrict__ su_part, const float* __restrict__ sv_part,
    float* __restrict__ fro)
{
    constexpr int BK = 64, KDIM = K2, NIT = KDIM / BK;   // 8 iters (even)
    __shared__ unsigned short As[2][4096];               // 16 KB
    __shared__ unsigned short Bs[2][8192];               // 32 KB (also C staging)
    const int t = threadIdx.x;
    const int bid = blockIdx.x;
    // XCD-aware swizzle: 512 blocks, 64-block contiguous chunks per XCD.
    const int wgid = (bid & 7) * 64 + (bid >> 3);
    const int bm = wgid >> 3, bn = wgid & 7;
    const int wave = t >> 6, lane = t & 63;
    const int wm = wave & 1, wn = wave >> 1;
    const int lrow = lane >> 3, lchunk = lane & 7;
    const int l15 = lane & 15, lq = lane >> 4;

    f32x4 acc[2][4] = {};

    auto LOADA = [&](int k0, bf16x8* v, float* g) {
        #pragma unroll
        for (int c = 0; c < 2; ++c) {
            const int row = (wave * 2 + c) * 8 + lrow;
            const int grow = bm * 64 + row;
            const int chunk = lchunk ^ lrow;
            v[c] = *(const bf16x8*)(vx + (size_t)grow * K2 + k0 + chunk * 8);
            g[c] = gate[(size_t)grow * NT + (k0 >> 3) + chunk];
        }
    };
    auto WRITEA = [&](int buf, const bf16x8* v, const float* g) {
        #pragma unroll
        for (int c = 0; c < 2; ++c) {
            bf16x8 o;
            #pragma unroll
            for (int e = 0; e < 8; ++e) {
                const float f = __builtin_bit_cast(float,
                    ((unsigned)(unsigned short)v[c][e]) << 16);
                o[e] = (short)(__builtin_bit_cast(unsigned, f * g[c]) >> 16);  // trunc
            }
            *(bf16x8*)&As[buf][(wave * 2 + c) * 512 + lane * 8] = o;
        }
    };
    auto STAGEB = [&](int buf, int k0) {
        #pragma unroll
        for (int c = 0; c < 4; ++c) {
            const int n_local = wave * 2 + (c >> 1);
            const int dblk = c & 1;
            const int n_glob = (k0 >> 3) + n_local;
            async16(&Bs[buf][(n_local * 2 + dblk) * 512],
                    Ub + (size_t)n_glob * (DMODEL * RANK)
                       + (size_t)(bn * 128 + dblk * 64 + lane) * RANK);
        }
    };
    auto COMPUTE = [&](int buf) {
        #pragma unroll
        for (int s = 0; s < 2; ++s) {
            bf16x8 af[2], bfr[4];
            const int kc = s * 4 + lq;   // = n_local
            #pragma unroll
            for (int i = 0; i < 2; ++i) {
                const int m = wm * 32 + i * 16 + l15;
                af[i] = *(const bf16x8*)&As[buf][m * BK + ((kc ^ (m & 7)) * 8)];
            }
            #pragma unroll
            for (int j = 0; j < 4; ++j) {
                const int cl = wn * 64 + j * 16 + l15;
                bfr[j] = *(const bf16x8*)&Bs[buf][((kc * 2 + (cl >> 6)) * 64 + (cl & 63)) * 8];
            }
            #pragma unroll
            for (int i = 0; i < 2; ++i)
                #pragma unroll
                for (int j = 0; j < 4; ++j)
                    acc[i][j] = __builtin_amdgcn_mfma_f32_16x16x32_bf16(
                        af[i], bfr[j], acc[i][j], 0, 0, 0);
        }
    };

    // 2-deep A pipeline (named reg sets), B async 1-ahead.
    bf16x8 v0[2], v1[2]; float g0[2], g1[2];
    LOADA(0, v0, g0);
    STAGEB(0, 0);
    WRITEA(0, v0, g0);             // tile 0 A -> LDS[0]
    LOADA(BK, v1, g1);             // tile 1 A in flight
    __syncthreads();
    for (int kt = 0; kt < NIT; kt += 2) {
        // iter kt: LDS[0] = tile kt; v1/g1 = tile kt+1 A-data
        if (kt + 2 < NIT) LOADA((kt + 2) * BK, v0, g0);
        STAGEB(1, (kt + 1) * BK);              // async B tile kt+1
        COMPUTE(0);
        WRITEA(1, v1, g1);                     // tile kt+1 A -> LDS[1]
        __syncthreads();
        // iter kt+1: LDS[1] = tile kt+1; v0/g0 = tile kt+2 A-data
        if (kt + 3 < NIT) LOADA((kt + 3) * BK, v1, g1);
        if (kt + 2 < NIT) STAGEB(0, (kt + 2) * BK);
        COMPUTE(1);
        if (kt + 2 < NIT) WRITEA(0, v0, g0);
        __syncthreads();
    }

    float* Cs = (float*)&Bs[0][0];   // 64x128 f32 = 32 KB
    #pragma unroll
    for (int i = 0; i < 2; ++i) {
        const int rowb = wm * 32 + i * 16 + lq * 4;
        #pragma unroll
        for (int j = 0; j < 4; ++j) {
            const int col = wn * 64 + j * 16 + l15;
            #pragma unroll
            for (int r = 0; r < 4; ++r)
                Cs[(rowb + r) * 128 + col] = acc[i][j][r];
        }
    }
    __syncthreads();
    #pragma unroll
    for (int p = 0; p < 8; ++p) {    // 512B-contiguous rows
        const int row = p * 8 + (t >> 5);
        const int col = (t & 31) * 4;
        *(f32x4*)&out[(size_t)(bm * 64 + row) * DMODEL + bn * 128 + col] =
            *(const f32x4*)&Cs[row * 128 + col];
    }

    // finalize Frobenius norms (K1 wrote su/sv; kernel boundary = coherence)
    if (bn == 0 && bm == 0 && t < NT) {
        fro[t] = sqrtf(su_part[t]) * sqrtf(sv_part[t]) / sqrtf((float)(DMODEL * RANK));
    }
}

extern "C" void kernel_launch(void* const* d_in, const int* in_sizes, int n_in,
                              void* d_out, int out_size, void* d_ws, size_t ws_size,
                              hipStream_t stream) {
    const float* x    = (const float*)d_in[0];
    const float* V    = (const float*)d_in[1];
    const float* U    = (const float*)d_in[2];
    const float* enc  = (const float*)d_in[3];
    const float* bias = (const float*)d_in[4];

    float* out  = (float*)d_out;                       // [4096,1024]
    float* gate = out + (size_t)BATCHN * DMODEL;       // [4096,64] fp32
    float* fro  = gate + (size_t)BATCHN * NT;          // [64]

    char* ws = (char*)d_ws;
    unsigned short* Ub = (unsigned short*)ws;                    // 1,048,576 B
    unsigned short* vx = (unsigned short*)(ws + 1048576);        // 4,194,304 B
    float* su_part     = (float*)(ws + 5242880);                 // 256 B
    float* sv_part     = (float*)(ws + 5244928);                 // 256 B

    gatevx_kernel<<<640, 256, 0, stream>>>(
        x, enc, V, U, bias, gate, vx, Ub, su_part, sv_part);
    out_kernel<<<512, 256, 0, stream>>>(
        vx, gate, Ub, out, su_part, sv_part, fro);
}

// Round 8
// 103.130 us; speedup vs baseline: 1.4725x; 1.0006x over previous
//
#include <hip/hip_runtime.h>
#include <math.h>

#define BATCHN 4096
#define DMODEL 1024
#define NT 64
#define RANK 8
#define K2 512   // NT*RANK

typedef __attribute__((ext_vector_type(8))) short bf16x8;
typedef __attribute__((ext_vector_type(4))) float f32x4;

__device__ __forceinline__ short f2bf(float f) {
    unsigned u = __builtin_bit_cast(unsigned, f);
    u += 0x7fffu + ((u >> 16) & 1u);   // round-to-nearest-even
    return (short)(u >> 16);
}

__device__ __forceinline__ bf16x8 cvt8(const float4 a, const float4 b) {
    bf16x8 o;
    o[0]=f2bf(a.x); o[1]=f2bf(a.y); o[2]=f2bf(a.z); o[3]=f2bf(a.w);
    o[4]=f2bf(b.x); o[5]=f2bf(b.y); o[6]=f2bf(b.z); o[7]=f2bf(b.w);
    return o;
}

// ---- K1: gate + raw-vx GEMM, fp32 inputs converted in-register.
// 1D grid 640, XCD-swizzled: wgid<576 -> GEMM (bm=wgid/9, bn=wgid%9);
// wgid>=576 -> U_n convert + su_part (n = wgid-576).
// 2-deep register prefetch: loads for tile t+2 issued at iter t (latency ~1.5 iters).
__global__ __launch_bounds__(256) void gatevx_kernel(
    const float* __restrict__ x, const float* __restrict__ enc,
    const float* __restrict__ V, const float* __restrict__ U,
    const float* __restrict__ bias,
    float* __restrict__ gate_out, unsigned short* __restrict__ vx_out,
    unsigned short* __restrict__ Ub,
    float* __restrict__ su_part, float* __restrict__ sv_part)
{
    __shared__ unsigned short As[2][4096];   // 8 KB x2 (epilogue reuses as C)
    __shared__ unsigned short Bs[2][4096];
    __shared__ float red[4];
    const int t = threadIdx.x;
    const int bid = blockIdx.x;
    // XCD-aware swizzle: 640 blocks, 8 XCDs, 80-block contiguous chunks.
    const int wgid = (bid & 7) * 80 + (bid >> 3);
    const int wave = t >> 6, lane = t & 63;

    if (wgid >= 576) {       // U convert + sumsq, one n per block
        const int n = wgid - 576;
        const size_t base = (size_t)n * 8192;
        float s = 0.f;
        #pragma unroll
        for (int it = 0; it < 4; ++it) {
            const size_t e = base + it * 2048 + t * 8;
            float4 v0 = *(const float4*)(U + e);
            float4 v1 = *(const float4*)(U + e + 4);
            *(bf16x8*)(Ub + e) = cvt8(v0, v1);
            s += v0.x*v0.x + v0.y*v0.y + v0.z*v0.z + v0.w*v0.w
               + v1.x*v1.x + v1.y*v1.y + v1.z*v1.z + v1.w*v1.w;
        }
        #pragma unroll
        for (int off = 32; off; off >>= 1) s += __shfl_down(s, off);
        if ((t & 63) == 0) red[t >> 6] = s;
        __syncthreads();
        if (t == 0) su_part[n] = red[0] + red[1] + red[2] + red[3];
        return;
    }

    constexpr int BK = 64, KDIM = DMODEL, NIT = KDIM / BK;  // 16 iters (even)
    const int bm = wgid / 9, bn = wgid % 9;
    const int wm = wave & 1, wn = wave >> 1;
    const int lrow = lane >> 3, lchunk = lane & 7;
    const int l15 = lane & 15, lq = lane >> 4;

    f32x4 acc[2][2] = {};
    const size_t Arow0 = (size_t)bm * 64;
    const float* Bbase = (bn == 0) ? enc : V + (size_t)(bn - 1) * 64 * DMODEL;
    const bool doSV = (bn >= 1) && (bm == 0);
    float sv[2] = {0.f, 0.f};

    auto LOADAB = [&](int k0, float4* a, float4* b) {
        #pragma unroll
        for (int c = 0; c < 2; ++c) {
            const int row = (wave * 2 + c) * 8 + lrow;
            const int chunk = lchunk ^ lrow;
            const float* ax = x + (Arow0 + row) * DMODEL + k0 + chunk * 8;
            a[c*2]   = *(const float4*)ax;
            a[c*2+1] = *(const float4*)(ax + 4);
            const float* bx = Bbase + (size_t)row * DMODEL + k0 + chunk * 8;
            b[c*2]   = *(const float4*)bx;
            b[c*2+1] = *(const float4*)(bx + 4);
        }
    };
    auto WRITEAB = [&](int buf, const float4* a, const float4* b) {
        #pragma unroll
        for (int c = 0; c < 2; ++c) {
            *(bf16x8*)&As[buf][(wave * 2 + c) * 512 + lane * 8] = cvt8(a[c*2], a[c*2+1]);
            *(bf16x8*)&Bs[buf][(wave * 2 + c) * 512 + lane * 8] = cvt8(b[c*2], b[c*2+1]);
            if (doSV) {
                const float4 b0 = b[c*2], b1 = b[c*2+1];
                sv[c] += b0.x*b0.x + b0.y*b0.y + b0.z*b0.z + b0.w*b0.w
                       + b1.x*b1.x + b1.y*b1.y + b1.z*b1.z + b1.w*b1.w;
            }
        }
    };
    auto COMPUTE = [&](int buf) {
        #pragma unroll
        for (int s = 0; s < 2; ++s) {
            bf16x8 af[2], bfr[2];
            const int kc = s * 4 + lq;
            #pragma unroll
            for (int i = 0; i < 2; ++i) {
                const int m = wm * 32 + i * 16 + l15;
                af[i] = *(const bf16x8*)&As[buf][m * BK + ((kc ^ (m & 7)) * 8)];
            }
            #pragma unroll
            for (int j = 0; j < 2; ++j) {
                const int n = wn * 32 + j * 16 + l15;
                bfr[j] = *(const bf16x8*)&Bs[buf][n * BK + ((kc ^ (n & 7)) * 8)];
            }
            #pragma unroll
            for (int i = 0; i < 2; ++i)
                #pragma unroll
                for (int j = 0; j < 2; ++j)
                    acc[i][j] = __builtin_amdgcn_mfma_f32_16x16x32_bf16(
                        af[i], bfr[j], acc[i][j], 0, 0, 0);
        }
    };

    // 2-deep pipeline, even-pair unrolled loop (named reg sets, no runtime index).
    float4 a0[4], b0[4], a1[4], b1[4];
    LOADAB(0, a0, b0);
    WRITEAB(0, a0, b0);            // tile 0 -> LDS[0]
    LOADAB(BK, a1, b1);            // tile 1 in flight
    __syncthreads();
    for (int kt = 0; kt < NIT; kt += 2) {
        // iter kt: LDS[0] = tile kt; a1/b1 = tile kt+1 data
        if (kt + 2 < NIT) LOADAB((kt + 2) * BK, a0, b0);
        COMPUTE(0);
        WRITEAB(1, a1, b1);        // tile kt+1 -> LDS[1] (loads issued 1.5 iters ago)
        __syncthreads();
        // iter kt+1: LDS[1] = tile kt+1; a0/b0 = tile kt+2 data
        if (kt + 3 < NIT) LOADAB((kt + 3) * BK, a1, b1);
        COMPUTE(1);
        if (kt + 2 < NIT) WRITEAB(0, a0, b0);
        __syncthreads();
    }

    if (doSV) {                        // finalize V sumsq: one n per (wave,c)
        #pragma unroll
        for (int c = 0; c < 2; ++c) {
            float s = sv[c];
            #pragma unroll
            for (int off = 32; off; off >>= 1) s += __shfl_down(s, off);
            if (lane == 0) sv_part[(bn - 1) * 8 + wave * 2 + c] = s;
        }
    }

    if (bn == 0) {
        float* Cs = (float*)&As[0][0];           // 64x64 f32 = 16 KB
        #pragma unroll
        for (int i = 0; i < 2; ++i) {
            const int rowb = wm * 32 + i * 16 + lq * 4;
            #pragma unroll
            for (int j = 0; j < 2; ++j) {
                const int col = wn * 32 + j * 16 + l15;
                const float bz = bias[col];
                #pragma unroll
                for (int r = 0; r < 4; ++r) {
                    const float p = acc[i][j][r] - bz;
                    Cs[(rowb + r) * 64 + col] = p > 0.f ? p : 0.f;
                }
            }
        }
        __syncthreads();
        #pragma unroll
        for (int p = 0; p < 4; ++p) {            // 256B-contiguous rows
            const int row = p * 16 + (t >> 4);
            const int col = (t & 15) * 4;
            *(f32x4*)&gate_out[(size_t)(bm * 64 + row) * NT + col] =
                *(const f32x4*)&Cs[row * 64 + col];
        }
    } else {
        unsigned short* Cs16 = &As[0][0];        // 64x64 bf16 = 8 KB
        #pragma unroll
        for (int i = 0; i < 2; ++i) {
            const int rowb = wm * 32 + i * 16 + lq * 4;
            #pragma unroll
            for (int j = 0; j < 2; ++j) {
                const int col = wn * 32 + j * 16 + l15;
                #pragma unroll
                for (int r = 0; r < 4; ++r)
                    Cs16[(rowb + r) * 64 + col] = (unsigned short)f2bf(acc[i][j][r]);
            }
        }
        __syncthreads();
        #pragma unroll
        for (int p = 0; p < 2; ++p) {            // 128B-contiguous row chunks
            const int row = p * 32 + (t >> 3);
            const int chunk = t & 7;
            *(bf16x8*)&vx_out[(size_t)(bm * 64 + row) * K2 + (bn - 1) * 64 + chunk * 8] =
                *(const bf16x8*)&Cs16[row * 64 + chunk * 8];
        }
    }
}

// ---- K2: out = (gate ⊙ vx) @ U^T (U native [n][d][r] bf16). 1D grid 512,
// XCD-swizzled. BM=64 BN=128 BK=64, KDIM=512. Gating folded into A-staging.
// BOTH A and B now 2-deep register-prefetched (B was async16 1-deep; its
// vmcnt(0)-at-barrier drain was the last exposed-latency path).
__global__ __launch_bounds__(256) void out_kernel(
    const unsigned short* __restrict__ vx, const float* __restrict__ gate,
    const unsigned short* __restrict__ Ub, float* __restrict__ out,
    const float* __restrict__ su_part, const float* __restrict__ sv_part,
    float* __restrict__ fro)
{
    constexpr int BK = 64, KDIM = K2, NIT = KDIM / BK;   // 8 iters (even)
    __shared__ unsigned short As[2][4096];               // 16 KB
    __shared__ unsigned short Bs[2][8192];               // 32 KB (also C staging)
    const int t = threadIdx.x;
    const int bid = blockIdx.x;
    // XCD-aware swizzle: 512 blocks, 64-block contiguous chunks per XCD.
    const int wgid = (bid & 7) * 64 + (bid >> 3);
    const int bm = wgid >> 3, bn = wgid & 7;
    const int wave = t >> 6, lane = t & 63;
    const int wm = wave & 1, wn = wave >> 1;
    const int lrow = lane >> 3, lchunk = lane & 7;
    const int l15 = lane & 15, lq = lane >> 4;

    f32x4 acc[2][4] = {};

    auto LOADA = [&](int k0, bf16x8* v, float* g) {
        #pragma unroll
        for (int c = 0; c < 2; ++c) {
            const int row = (wave * 2 + c) * 8 + lrow;
            const int grow = bm * 64 + row;
            const int chunk = lchunk ^ lrow;
            v[c] = *(const bf16x8*)(vx + (size_t)grow * K2 + k0 + chunk * 8);
            g[c] = gate[(size_t)grow * NT + (k0 >> 3) + chunk];
        }
    };
    auto WRITEA = [&](int buf, const bf16x8* v, const float* g) {
        #pragma unroll
        for (int c = 0; c < 2; ++c) {
            bf16x8 o;
            #pragma unroll
            for (int e = 0; e < 8; ++e) {
                const float f = __builtin_bit_cast(float,
                    ((unsigned)(unsigned short)v[c][e]) << 16);
                o[e] = (short)(__builtin_bit_cast(unsigned, f * g[c]) >> 16);  // trunc
            }
            *(bf16x8*)&As[buf][(wave * 2 + c) * 512 + lane * 8] = o;
        }
    };
    // B reg-staging: same per-lane addresses the old async16 produced.
    auto LOADB = [&](int k0, bf16x8* u) {
        #pragma unroll
        for (int c = 0; c < 4; ++c) {
            const int n_local = wave * 2 + (c >> 1);
            const int dblk = c & 1;
            const int n_glob = (k0 >> 3) + n_local;
            u[c] = *(const bf16x8*)(Ub + (size_t)n_glob * (DMODEL * RANK)
                       + (size_t)(bn * 128 + dblk * 64 + lane) * RANK);
        }
    };
    auto WRITEB = [&](int buf, const bf16x8* u) {
        #pragma unroll
        for (int c = 0; c < 4; ++c) {
            const int n_local = wave * 2 + (c >> 1);
            const int dblk = c & 1;
            *(bf16x8*)&Bs[buf][(n_local * 2 + dblk) * 512 + lane * 8] = u[c];
        }
    };
    auto COMPUTE = [&](int buf) {
        #pragma unroll
        for (int s = 0; s < 2; ++s) {
            bf16x8 af[2], bfr[4];
            const int kc = s * 4 + lq;   // = n_local
            #pragma unroll
            for (int i = 0; i < 2; ++i) {
                const int m = wm * 32 + i * 16 + l15;
                af[i] = *(const bf16x8*)&As[buf][m * BK + ((kc ^ (m & 7)) * 8)];
            }
            #pragma unroll
            for (int j = 0; j < 4; ++j) {
                const int cl = wn * 64 + j * 16 + l15;
                bfr[j] = *(const bf16x8*)&Bs[buf][((kc * 2 + (cl >> 6)) * 64 + (cl & 63)) * 8];
            }
            #pragma unroll
            for (int i = 0; i < 2; ++i)
                #pragma unroll
                for (int j = 0; j < 4; ++j)
                    acc[i][j] = __builtin_amdgcn_mfma_f32_16x16x32_bf16(
                        af[i], bfr[j], acc[i][j], 0, 0, 0);
        }
    };

    // 2-deep pipeline on BOTH operands (named reg sets, no runtime index).
    bf16x8 v0[2], v1[2]; float g0[2], g1[2];
    bf16x8 u0[4], u1[4];
    LOADA(0, v0, g0);  LOADB(0, u0);
    WRITEA(0, v0, g0); WRITEB(0, u0);     // tile 0 -> LDS[0]
    LOADA(BK, v1, g1); LOADB(BK, u1);     // tile 1 in flight
    __syncthreads();
    for (int kt = 0; kt < NIT; kt += 2) {
        // iter kt: LDS[0] = tile kt; v1/g1/u1 = tile kt+1 data
        if (kt + 2 < NIT) { LOADA((kt + 2) * BK, v0, g0); LOADB((kt + 2) * BK, u0); }
        COMPUTE(0);
        WRITEA(1, v1, g1); WRITEB(1, u1); // tile kt+1 -> LDS[1]
        __syncthreads();
        // iter kt+1: LDS[1] = tile kt+1; v0/g0/u0 = tile kt+2 data
        if (kt + 3 < NIT) { LOADA((kt + 3) * BK, v1, g1); LOADB((kt + 3) * BK, u1); }
        COMPUTE(1);
        if (kt + 2 < NIT) { WRITEA(0, v0, g0); WRITEB(0, u0); }
        __syncthreads();
    }

    float* Cs = (float*)&Bs[0][0];   // 64x128 f32 = 32 KB
    #pragma unroll
    for (int i = 0; i < 2; ++i) {
        const int rowb = wm * 32 + i * 16 + lq * 4;
        #pragma unroll
        for (int j = 0; j < 4; ++j) {
            const int col = wn * 64 + j * 16 + l15;
            #pragma unroll
            for (int r = 0; r < 4; ++r)
                Cs[(rowb + r) * 128 + col] = acc[i][j][r];
        }
    }
    __syncthreads();
    #pragma unroll
    for (int p = 0; p < 8; ++p) {    // 512B-contiguous rows
        const int row = p * 8 + (t >> 5);
        const int col = (t & 31) * 4;
        *(f32x4*)&out[(size_t)(bm * 64 + row) * DMODEL + bn * 128 + col] =
            *(const f32x4*)&Cs[row * 128 + col];
    }

    // finalize Frobenius norms (K1 wrote su/sv; kernel boundary = coherence)
    if (bn == 0 && bm == 0 && t < NT) {
        fro[t] = sqrtf(su_part[t]) * sqrtf(sv_part[t]) / sqrtf((float)(DMODEL * RANK));
    }
}

extern "C" void kernel_launch(void* const* d_in, const int* in_sizes, int n_in,
                              void* d_out, int out_size, void* d_ws, size_t ws_size,
                              hipStream_t stream) {
    const float* x    = (const float*)d_in[0];
    const float* V    = (const float*)d_in[1];
    const float* U    = (const float*)d_in[2];
    const float* enc  = (const float*)d_in[3];
    const float* bias = (const float*)d_in[4];

    float* out  = (float*)d_out;                       // [4096,1024]
    float* gate = out + (size_t)BATCHN * DMODEL;       // [4096,64] fp32
    float* fro  = gate + (size_t)BATCHN * NT;          // [64]

    char* ws = (char*)d_ws;
    unsigned short* Ub = (unsigned short*)ws;                    // 1,048,576 B
    unsigned short* vx = (unsigned short*)(ws + 1048576);        // 4,194,304 B
    float* su_part     = (float*)(ws + 5242880);                 // 256 B
    float* sv_part     = (float*)(ws + 5244928);                 // 256 B

    gatevx_kernel<<<640, 256, 0, stream>>>(
        x, enc, V, U, bias, gate, vx, Ub, su_part, sv_part);
    out_kernel<<<512, 256, 0, stream>>>(
        vx, gate, Ub, out, su_part, sv_part, fro);
}

// Round 9
// 102.572 us; speedup vs baseline: 1.4805x; 1.0054x over previous
//
#include <hip/hip_runtime.h>
#include <hip/hip_bf16.h>
#include <math.h>

#define BATCHN 4096
#define DMODEL 1024
#define NT 64
#define RANK 8
#define K2 512   // NT*RANK

typedef __attribute__((ext_vector_type(8))) short bf16x8;
typedef __attribute__((ext_vector_type(4))) float f32x4;

// RNE f32->bf16 via the compiler's native path: hipcc fuses adjacent casts
// into v_cvt_pk_bf16_f32 (1 inst / 2 elems) -- the hand-rolled bit-manip
// version blocked this (≈6 VALU insts / elem in the staging hot loop).
__device__ __forceinline__ short f2bf(float f) {
    return __builtin_bit_cast(short, __float2bfloat16(f));
}

__device__ __forceinline__ bf16x8 cvt8(const float4 a, const float4 b) {
    bf16x8 o;
    o[0]=f2bf(a.x); o[1]=f2bf(a.y); o[2]=f2bf(a.z); o[3]=f2bf(a.w);
    o[4]=f2bf(b.x); o[5]=f2bf(b.y); o[6]=f2bf(b.z); o[7]=f2bf(b.w);
    return o;
}

// ---- K1: gate + raw-vx GEMM, fp32 inputs converted in-register.
// 1D grid 640, XCD-swizzled: wgid<576 -> GEMM (bm=wgid/9, bn=wgid%9);
// wgid>=576 -> U_n convert + su_part (n = wgid-576).
// 2-deep register prefetch: loads for tile t+2 issued at iter t (latency ~1.5 iters).
__global__ __launch_bounds__(256) void gatevx_kernel(
    const float* __restrict__ x, const float* __restrict__ enc,
    const float* __restrict__ V, const float* __restrict__ U,
    const float* __restrict__ bias,
    float* __restrict__ gate_out, unsigned short* __restrict__ vx_out,
    unsigned short* __restrict__ Ub,
    float* __restrict__ su_part, float* __restrict__ sv_part)
{
    __shared__ unsigned short As[2][4096];   // 8 KB x2 (epilogue reuses as C)
    __shared__ unsigned short Bs[2][4096];
    __shared__ float red[4];
    const int t = threadIdx.x;
    const int bid = blockIdx.x;
    // XCD-aware swizzle: 640 blocks, 8 XCDs, 80-block contiguous chunks.
    const int wgid = (bid & 7) * 80 + (bid >> 3);
    const int wave = t >> 6, lane = t & 63;

    if (wgid >= 576) {       // U convert + sumsq, one n per block
        const int n = wgid - 576;
        const size_t base = (size_t)n * 8192;
        float s = 0.f;
        #pragma unroll
        for (int it = 0; it < 4; ++it) {
            const size_t e = base + it * 2048 + t * 8;
            float4 v0 = *(const float4*)(U + e);
            float4 v1 = *(const float4*)(U + e + 4);
            *(bf16x8*)(Ub + e) = cvt8(v0, v1);
            s += v0.x*v0.x + v0.y*v0.y + v0.z*v0.z + v0.w*v0.w
               + v1.x*v1.x + v1.y*v1.y + v1.z*v1.z + v1.w*v1.w;
        }
        #pragma unroll
        for (int off = 32; off; off >>= 1) s += __shfl_down(s, off);
        if ((t & 63) == 0) red[t >> 6] = s;
        __syncthreads();
        if (t == 0) su_part[n] = red[0] + red[1] + red[2] + red[3];
        return;
    }

    constexpr int BK = 64, KDIM = DMODEL, NIT = KDIM / BK;  // 16 iters (even)
    const int bm = wgid / 9, bn = wgid % 9;
    const int wm = wave & 1, wn = wave >> 1;
    const int lrow = lane >> 3, lchunk = lane & 7;
    const int l15 = lane & 15, lq = lane >> 4;

    f32x4 acc[2][2] = {};
    const size_t Arow0 = (size_t)bm * 64;
    const float* Bbase = (bn == 0) ? enc : V + (size_t)(bn - 1) * 64 * DMODEL;
    const bool doSV = (bn >= 1) && (bm == 0);
    float sv[2] = {0.f, 0.f};

    auto LOADAB = [&](int k0, float4* a, float4* b) {
        #pragma unroll
        for (int c = 0; c < 2; ++c) {
            const int row = (wave * 2 + c) * 8 + lrow;
            const int chunk = lchunk ^ lrow;
            const float* ax = x + (Arow0 + row) * DMODEL + k0 + chunk * 8;
            a[c*2]   = *(const float4*)ax;
            a[c*2+1] = *(const float4*)(ax + 4);
            const float* bx = Bbase + (size_t)row * DMODEL + k0 + chunk * 8;
            b[c*2]   = *(const float4*)bx;
            b[c*2+1] = *(const float4*)(bx + 4);
        }
    };
    auto WRITEAB = [&](int buf, const float4* a, const float4* b) {
        #pragma unroll
        for (int c = 0; c < 2; ++c) {
            *(bf16x8*)&As[buf][(wave * 2 + c) * 512 + lane * 8] = cvt8(a[c*2], a[c*2+1]);
            *(bf16x8*)&Bs[buf][(wave * 2 + c) * 512 + lane * 8] = cvt8(b[c*2], b[c*2+1]);
            if (doSV) {
                const float4 b0 = b[c*2], b1 = b[c*2+1];
                sv[c] += b0.x*b0.x + b0.y*b0.y + b0.z*b0.z + b0.w*b0.w
                       + b1.x*b1.x + b1.y*b1.y + b1.z*b1.z + b1.w*b1.w;
            }
        }
    };
    auto COMPUTE = [&](int buf) {
        #pragma unroll
        for (int s = 0; s < 2; ++s) {
            bf16x8 af[2], bfr[2];
            const int kc = s * 4 + lq;
            #pragma unroll
            for (int i = 0; i < 2; ++i) {
                const int m = wm * 32 + i * 16 + l15;
                af[i] = *(const bf16x8*)&As[buf][m * BK + ((kc ^ (m & 7)) * 8)];
            }
            #pragma unroll
            for (int j = 0; j < 2; ++j) {
                const int n = wn * 32 + j * 16 + l15;
                bfr[j] = *(const bf16x8*)&Bs[buf][n * BK + ((kc ^ (n & 7)) * 8)];
            }
            #pragma unroll
            for (int i = 0; i < 2; ++i)
                #pragma unroll
                for (int j = 0; j < 2; ++j)
                    acc[i][j] = __builtin_amdgcn_mfma_f32_16x16x32_bf16(
                        af[i], bfr[j], acc[i][j], 0, 0, 0);
        }
    };

    // 2-deep pipeline, even-pair unrolled loop (named reg sets, no runtime index).
    float4 a0[4], b0[4], a1[4], b1[4];
    LOADAB(0, a0, b0);
    WRITEAB(0, a0, b0);            // tile 0 -> LDS[0]
    LOADAB(BK, a1, b1);            // tile 1 in flight
    __syncthreads();
    for (int kt = 0; kt < NIT; kt += 2) {
        // iter kt: LDS[0] = tile kt; a1/b1 = tile kt+1 data
        if (kt + 2 < NIT) LOADAB((kt + 2) * BK, a0, b0);
        COMPUTE(0);
        WRITEAB(1, a1, b1);        // tile kt+1 -> LDS[1] (loads issued 1.5 iters ago)
        __syncthreads();
        // iter kt+1: LDS[1] = tile kt+1; a0/b0 = tile kt+2 data
        if (kt + 3 < NIT) LOADAB((kt + 3) * BK, a1, b1);
        COMPUTE(1);
        if (kt + 2 < NIT) WRITEAB(0, a0, b0);
        __syncthreads();
    }

    if (doSV) {                        // finalize V sumsq: one n per (wave,c)
        #pragma unroll
        for (int c = 0; c < 2; ++c) {
            float s = sv[c];
            #pragma unroll
            for (int off = 32; off; off >>= 1) s += __shfl_down(s, off);
            if (lane == 0) sv_part[(bn - 1) * 8 + wave * 2 + c] = s;
        }
    }

    if (bn == 0) {
        float* Cs = (float*)&As[0][0];           // 64x64 f32 = 16 KB
        #pragma unroll
        for (int i = 0; i < 2; ++i) {
            const int rowb = wm * 32 + i * 16 + lq * 4;
            #pragma unroll
            for (int j = 0; j < 2; ++j) {
                const int col = wn * 32 + j * 16 + l15;
                const float bz = bias[col];
                #pragma unroll
                for (int r = 0; r < 4; ++r) {
                    const float p = acc[i][j][r] - bz;
                    Cs[(rowb + r) * 64 + col] = p > 0.f ? p : 0.f;
                }
            }
        }
        __syncthreads();
        #pragma unroll
        for (int p = 0; p < 4; ++p) {            // 256B-contiguous rows
            const int row = p * 16 + (t >> 4);
            const int col = (t & 15) * 4;
            *(f32x4*)&gate_out[(size_t)(bm * 64 + row) * NT + col] =
                *(const f32x4*)&Cs[row * 64 + col];
        }
    } else {
        unsigned short* Cs16 = &As[0][0];        // 64x64 bf16 = 8 KB
        #pragma unroll
        for (int i = 0; i < 2; ++i) {
            const int rowb = wm * 32 + i * 16 + lq * 4;
            #pragma unroll
            for (int j = 0; j < 2; ++j) {
                const int col = wn * 32 + j * 16 + l15;
                #pragma unroll
                for (int r = 0; r < 4; ++r)
                    Cs16[(rowb + r) * 64 + col] = (unsigned short)f2bf(acc[i][j][r]);
            }
        }
        __syncthreads();
        #pragma unroll
        for (int p = 0; p < 2; ++p) {            // 128B-contiguous row chunks
            const int row = p * 32 + (t >> 3);
            const int chunk = t & 7;
            *(bf16x8*)&vx_out[(size_t)(bm * 64 + row) * K2 + (bn - 1) * 64 + chunk * 8] =
                *(const bf16x8*)&Cs16[row * 64 + chunk * 8];
        }
    }
}

// ---- K2: out = (gate ⊙ vx) @ U^T (U native [n][d][r] bf16). 1D grid 512,
// XCD-swizzled. BM=64 BN=128 BK=64, KDIM=512. Gating folded into A-staging.
// Both operands 2-deep register-prefetched.
__global__ __launch_bounds__(256) void out_kernel(
    const unsigned short* __restrict__ vx, const float* __restrict__ gate,
    const unsigned short* __restrict__ Ub, float* __restrict__ out,
    const float* __restrict__ su_part, const float* __restrict__ sv_part,
    float* __restrict__ fro)
{
    constexpr int BK = 64, KDIM = K2, NIT = KDIM / BK;   // 8 iters (even)
    __shared__ unsigned short As[2][4096];               // 16 KB
    __shared__ unsigned short Bs[2][8192];               // 32 KB (also C staging)
    const int t = threadIdx.x;
    const int bid = blockIdx.x;
    // XCD-aware swizzle: 512 blocks, 64-block contiguous chunks per XCD.
    const int wgid = (bid & 7) * 64 + (bid >> 3);
    const int bm = wgid >> 3, bn = wgid & 7;
    const int wave = t >> 6, lane = t & 63;
    const int wm = wave & 1, wn = wave >> 1;
    const int lrow = lane >> 3, lchunk = lane & 7;
    const int l15 = lane & 15, lq = lane >> 4;

    f32x4 acc[2][4] = {};

    auto LOADA = [&](int k0, bf16x8* v, float* g) {
        #pragma unroll
        for (int c = 0; c < 2; ++c) {
            const int row = (wave * 2 + c) * 8 + lrow;
            const int grow = bm * 64 + row;
            const int chunk = lchunk ^ lrow;
            v[c] = *(const bf16x8*)(vx + (size_t)grow * K2 + k0 + chunk * 8);
            g[c] = gate[(size_t)grow * NT + (k0 >> 3) + chunk];
        }
    };
    auto WRITEA = [&](int buf, const bf16x8* v, const float* g) {
        #pragma unroll
        for (int c = 0; c < 2; ++c) {
            bf16x8 o;
            #pragma unroll
            for (int e = 0; e < 8; ++e) {
                const float f = __builtin_bit_cast(float,
                    ((unsigned)(unsigned short)v[c][e]) << 16);
                o[e] = f2bf(f * g[c]);           // native cvt path (was manual trunc)
            }
            *(bf16x8*)&As[buf][(wave * 2 + c) * 512 + lane * 8] = o;
        }
    };
    // B reg-staging: same per-lane addresses the old async16 produced.
    auto LOADB = [&](int k0, bf16x8* u) {
        #pragma unroll
        for (int c = 0; c < 4; ++c) {
            const int n_local = wave * 2 + (c >> 1);
            const int dblk = c & 1;
            const int n_glob = (k0 >> 3) + n_local;
            u[c] = *(const bf16x8*)(Ub + (size_t)n_glob * (DMODEL * RANK)
                       + (size_t)(bn * 128 + dblk * 64 + lane) * RANK);
        }
    };
    auto WRITEB = [&](int buf, const bf16x8* u) {
        #pragma unroll
        for (int c = 0; c < 4; ++c) {
            const int n_local = wave * 2 + (c >> 1);
            const int dblk = c & 1;
            *(bf16x8*)&Bs[buf][(n_local * 2 + dblk) * 512 + lane * 8] = u[c];
        }
    };
    auto COMPUTE = [&](int buf) {
        #pragma unroll
        for (int s = 0; s < 2; ++s) {
            bf16x8 af[2], bfr[4];
            const int kc = s * 4 + lq;   // = n_local
            #pragma unroll
            for (int i = 0; i < 2; ++i) {
                const int m = wm * 32 + i * 16 + l15;
                af[i] = *(const bf16x8*)&As[buf][m * BK + ((kc ^ (m & 7)) * 8)];
            }
            #pragma unroll
            for (int j = 0; j < 4; ++j) {
                const int cl = wn * 64 + j * 16 + l15;
                bfr[j] = *(const bf16x8*)&Bs[buf][((kc * 2 + (cl >> 6)) * 64 + (cl & 63)) * 8];
            }
            #pragma unroll
            for (int i = 0; i < 2; ++i)
                #pragma unroll
                for (int j = 0; j < 4; ++j)
                    acc[i][j] = __builtin_amdgcn_mfma_f32_16x16x32_bf16(
                        af[i], bfr[j], acc[i][j], 0, 0, 0);
        }
    };

    // 2-deep pipeline on BOTH operands (named reg sets, no runtime index).
    bf16x8 v0[2], v1[2]; float g0[2], g1[2];
    bf16x8 u0[4], u1[4];
    LOADA(0, v0, g0);  LOADB(0, u0);
    WRITEA(0, v0, g0); WRITEB(0, u0);     // tile 0 -> LDS[0]
    LOADA(BK, v1, g1); LOADB(BK, u1);     // tile 1 in flight
    __syncthreads();
    for (int kt = 0; kt < NIT; kt += 2) {
        // iter kt: LDS[0] = tile kt; v1/g1/u1 = tile kt+1 data
        if (kt + 2 < NIT) { LOADA((kt + 2) * BK, v0, g0); LOADB((kt + 2) * BK, u0); }
        COMPUTE(0);
        WRITEA(1, v1, g1); WRITEB(1, u1); // tile kt+1 -> LDS[1]
        __syncthreads();
        // iter kt+1: LDS[1] = tile kt+1; v0/g0/u0 = tile kt+2 data
        if (kt + 3 < NIT) { LOADA((kt + 3) * BK, v1, g1); LOADB((kt + 3) * BK, u1); }
        COMPUTE(1);
        if (kt + 2 < NIT) { WRITEA(0, v0, g0); WRITEB(0, u0); }
        __syncthreads();
    }

    float* Cs = (float*)&Bs[0][0];   // 64x128 f32 = 32 KB
    #pragma unroll
    for (int i = 0; i < 2; ++i) {
        const int rowb = wm * 32 + i * 16 + lq * 4;
        #pragma unroll
        for (int j = 0; j < 4; ++j) {
            const int col = wn * 64 + j * 16 + l15;
            #pragma unroll
            for (int r = 0; r < 4; ++r)
                Cs[(rowb + r) * 128 + col] = acc[i][j][r];
        }
    }
    __syncthreads();
    #pragma unroll
    for (int p = 0; p < 8; ++p) {    // 512B-contiguous rows
        const int row = p * 8 + (t >> 5);
        const int col = (t & 31) * 4;
        *(f32x4*)&out[(size_t)(bm * 64 + row) * DMODEL + bn * 128 + col] =
            *(const f32x4*)&Cs[row * 128 + col];
    }

    // finalize Frobenius norms (K1 wrote su/sv; kernel boundary = coherence)
    if (bn == 0 && bm == 0 && t < NT) {
        fro[t] = sqrtf(su_part[t]) * sqrtf(sv_part[t]) / sqrtf((float)(DMODEL * RANK));
    }
}

extern "C" void kernel_launch(void* const* d_in, const int* in_sizes, int n_in,
                              void* d_out, int out_size, void* d_ws, size_t ws_size,
                              hipStream_t stream) {
    const float* x    = (const float*)d_in[0];
    const float* V    = (const float*)d_in[1];
    const float* U    = (const float*)d_in[2];
    const float* enc  = (const float*)d_in[3];
    const float* bias = (const float*)d_in[4];

    float* out  = (float*)d_out;                       // [4096,1024]
    float* gate = out + (size_t)BATCHN * DMODEL;       // [4096,64] fp32
    float* fro  = gate + (size_t)BATCHN * NT;          // [64]

    char* ws = (char*)d_ws;
    unsigned short* Ub = (unsigned short*)ws;                    // 1,048,576 B
    unsigned short* vx = (unsigned short*)(ws + 1048576);        // 4,194,304 B
    float* su_part     = (float*)(ws + 5242880);                 // 256 B
    float* sv_part     = (float*)(ws + 5244928);                 // 256 B

    gatevx_kernel<<<640, 256, 0, stream>>>(
        x, enc, V, U, bias, gate, vx, Ub, su_part, sv_part);
    out_kernel<<<512, 256, 0, stream>>>(
        vx, gate, Ub, out, su_part, sv_part, fro);
}